// Round 7
// baseline (412.332 us; speedup 1.0000x reference)
//
#include <hip/hip_runtime.h>
#include <math.h>

// EdgeEmbedding, R7: runtime-fill discriminator. Four structural write variants
// (R0 1-store/thread, R6 8-store, R4 24-store zero pass, R3 nt) all run the 402 MB
// output at ~3 TB/s while fillBufferAligned hits 6.2 TB/s on the same buffer.
// Theory: in the timed graph our window inherits a fully-dirty L2/L3 from the 1.6 GB
// poison fill and pays the drain. Test: use the runtime's OWN fill (hipMemsetAsync ->
// fillBufferAligned) for the zero phase, then the verified sparse edge kernel.
// If memset hits 6 TB/s here, the cap was our codegen (keep this, ~-45 us).
// If memset also runs ~3 TB/s, the window is the cap -> declare roofline at R0.

#define NATOMS 2048
#define NBASIS 20
#define RCUT   5.0f

#define DIR_OFF   ((long long)NATOMS * NATOMS * NBASIS)        // floats
#define MASK_OFF  ((long long)NATOMS * NATOMS * (NBASIS + 3))  // floats
#define OUT_BYTES ((size_t)NATOMS * NATOMS * (NBASIS + 4) * 4) // 402,653,184 B

#define EBLOCK 256   // 8 blocks per row -> i is blockIdx-uniform (scalar pos[i] loads)

__global__ __launch_bounds__(EBLOCK) void edge_sparse_kernel(
    const float* __restrict__ pos, float* __restrict__ out)
{
    const int i = blockIdx.x >> 3;                         // 2048 rows
    const int j = ((blockIdx.x & 7) << 8) | threadIdx.x;   // 8*256 = 2048 cols

    const float xi = pos[3 * i + 0], yi = pos[3 * i + 1], zi = pos[3 * i + 2];
    const float xj = pos[3 * j + 0], yj = pos[3 * j + 1], zj = pos[3 * j + 2];
    const float dx = xi - xj, dy = yi - yj, dz = zi - zj;
    float d2;
    {
        // match numpy's unfused rounding so the dist<r mask can't flip at the boundary
#pragma clang fp contract(off)
        d2 = (dx * dx + dy * dy) + dz * dz;
    }
    const float dist = sqrtf(d2);
    if (!((dist < RCUT) && (i != j))) return;   // 99.2% of lanes exit here

    const float x  = dist * (1.0f / RCUT);
    const float x2 = x * x, x4 = x2 * x2, x8 = x4 * x4, x9 = x8 * x;
    const float env   = 1.0f - 55.0f * x9 + 99.0f * x9 * x - 45.0f * x9 * x2;
    const float scale = env / x;
    const float theta = 3.14159265358979323846f * x;
    const float twoc  = 2.0f * cosf(theta);

    const long long pair = (long long)i * NATOMS + j;
    float4* __restrict__ de = (float4*)out;
#pragma unroll
    for (int g = 0; g < 5; ++g) {
        // identical numeric structure to the verified kernel: two sinf seeds per
        // group of 4, two Chebyshev recurrence steps
        const float k0 = (float)(4 * g + 1);
        const float s0 = sinf(k0 * theta);
        const float s1 = sinf((k0 + 1.0f) * theta);
        const float s2 = twoc * s1 - s0;
        const float s3 = twoc * s2 - s1;
        de[pair * 5 + g] = make_float4(scale * s0, scale * s1, scale * s2, scale * s3);
    }

    const float inv = 1.0f / dist;
    float* __restrict__ dir = out + DIR_OFF + pair * 3;
    dir[0] = dx * inv; dir[1] = dy * inv; dir[2] = dz * inv;
    out[MASK_OFF + pair] = 1.0f;
}

extern "C" void kernel_launch(void* const* d_in, const int* in_sizes, int n_in,
                              void* d_out, int out_size, void* d_ws, size_t ws_size,
                              hipStream_t stream) {
    const float* pos = (const float*)d_in[0];
    // Phase 1: zero the 402.65 MB output via the runtime's optimized fill path
    // (the same fillBufferAligned kernel that measures 6.2 TB/s in this harness).
    hipMemsetAsync(d_out, 0, OUT_BYTES, stream);
    // Phase 2: sparse edges only (same stream -> ordered after the zero pass).
    edge_sparse_kernel<<<dim3(NATOMS * (NATOMS / EBLOCK)), dim3(EBLOCK), 0, stream>>>(
        pos, (float*)d_out);
}

// Round 8
// 395.673 us; speedup vs baseline: 1.0421x; 1.0421x over previous
//
#include <hip/hip_runtime.h>
#include <math.h>

// EdgeEmbedding: pos[2048,3] f32 -> (dist_edge[N,N,20], dir_edge[N,N,3], mask[N,N]) f32.
// FINAL (R8 = revert to verified R0, the best measured variant at 395.99 us).
// Roofline evidence (R3-R7): five structurally different write strategies — including
// hipMemsetAsync's own fillBufferAligned, which measures 6.2 TB/s elsewhere in this
// same timed sequence — all run ~3 TB/s effective in OUR slot (~136-160 us for 402 MB).
// The slot follows the harness's 1.6 GB poison fill; its dirty L2+LLC (~288 MB) drains
// into our write window. Floor = (402 MB + ~288 MB)/6.29 TB/s + overhead ~= 125-135 us;
// this kernel's ~136 us portion sits on it. Structure: 5 threads/pair -> each lane
// stores one contiguous float4 of the 20-basis row (perfectly coalesced); wave 0
// handles dir (stride-12B, data-footprint-limited) + mask (coalesced).

#define NATOMS 2048
#define NBASIS 20
#define RCUT   5.0f
#define PAIRS_PER_BLOCK 64
#define BLOCK_THREADS   320   // 64 pairs * 5 quad-slots; addr = base + 16*t, contiguous per wave

__global__ __launch_bounds__(BLOCK_THREADS) void edge_embed_kernel(
    const float* __restrict__ pos, float* __restrict__ out)
{
    const int t = threadIdx.x;
    const int blocksPerRow = NATOMS / PAIRS_PER_BLOCK;          // 32
    const int i  = blockIdx.x / blocksPerRow;                   // wave-uniform
    const int j0 = (blockIdx.x % blocksPerRow) * PAIRS_PER_BLOCK;

    const int p = t / 5;            // pair slot 0..63
    const int q = t - 5 * p;        // quad 0..4 (k = 4q+1 .. 4q+4)
    const int j = j0 + p;

    const float xi = pos[3 * i + 0], yi = pos[3 * i + 1], zi = pos[3 * i + 2];
    const float xj = pos[3 * j + 0], yj = pos[3 * j + 1], zj = pos[3 * j + 2];
    const float dx = xi - xj, dy = yi - yj, dz = zi - zj;
    float d2;
    {
        // match numpy's unfused rounding so the dist<r mask can't flip at the boundary
#pragma clang fp contract(off)
        d2 = (dx * dx + dy * dy) + dz * dz;
    }
    const float dist = sqrtf(d2);
    const bool m = (dist < RCUT) && (i != j);

    float4 v = make_float4(0.0f, 0.0f, 0.0f, 0.0f);
    if (m) {   // ~0.8% of lanes
        const float x  = dist * (1.0f / RCUT);
        const float x2 = x * x, x4 = x2 * x2, x8 = x4 * x4, x9 = x8 * x;
        const float env = 1.0f - 55.0f * x9 + 99.0f * x9 * x - 45.0f * x9 * x2;
        const float scale = env / x;
        const float theta = 3.14159265358979323846f * x;
        const float k0 = (float)(4 * q + 1);
        const float s0 = sinf(k0 * theta);
        const float s1 = sinf((k0 + 1.0f) * theta);
        const float twoc = 2.0f * cosf(theta);
        const float s2 = twoc * s1 - s0;
        const float s3 = twoc * s2 - s1;
        v = make_float4(scale * s0, scale * s1, scale * s2, scale * s3);
    }

    const long long pair = (long long)i * NATOMS + j;
    float4* __restrict__ de = (float4*)out;
    de[pair * 5 + q] = v;   // = quad index pair0*5 + t -> contiguous 16B per lane

    if (t < PAIRS_PER_BLOCK) {
        // wave 0: dir (3 dwords, stride 12B -> 12 lines/instr = data footprint) + mask (coalesced)
        const int j2 = j0 + t;
        const float xj2 = pos[3 * j2 + 0], yj2 = pos[3 * j2 + 1], zj2 = pos[3 * j2 + 2];
        const float ex = xi - xj2, ey = yi - yj2, ez = zi - zj2;
        float e2;
        {
#pragma clang fp contract(off)
            e2 = (ex * ex + ey * ey) + ez * ez;
        }
        const float ed = sqrtf(e2);
        const bool m2 = (ed < RCUT) && (i != j2);
        float ox = 0.0f, oy = 0.0f, oz = 0.0f, mv = 0.0f;
        if (m2) { ox = ex / ed; oy = ey / ed; oz = ez / ed; mv = 1.0f; }
        const long long pair2 = (long long)i * NATOMS + j2;
        float* __restrict__ dir = out + (long long)NATOMS * NATOMS * NBASIS + pair2 * 3;
        float* __restrict__ mk  = out + (long long)NATOMS * NATOMS * (NBASIS + 3) + pair2;
        dir[0] = ox; dir[1] = oy; dir[2] = oz;
        *mk = mv;
    }
}

extern "C" void kernel_launch(void* const* d_in, const int* in_sizes, int n_in,
                              void* d_out, int out_size, void* d_ws, size_t ws_size,
                              hipStream_t stream) {
    const float* pos = (const float*)d_in[0];
    float* out = (float*)d_out;
    // 2048 rows * 32 blocks/row, 320 threads (64 pairs x 5) per block
    edge_embed_kernel<<<dim3(NATOMS * (NATOMS / PAIRS_PER_BLOCK)), dim3(BLOCK_THREADS), 0, stream>>>(pos, out);
}